// Round 1
// baseline (702.787 us; speedup 1.0000x reference)
//
#include <hip/hip_runtime.h>
#include <cstdint>

#define NB 8
#define NA 100000
#define NC 80
#define TOPN 1000
#define MAXOBJ 100
#define CAND_CAP 2048
#define MIN_SCORE 0.05f
#define NMS_THR 0.5f

// ---------------- K1: per-anchor max/argmax over classes + key + hist pass 1 ----------------
__global__ void k_scores(const float* __restrict__ cls, unsigned int* __restrict__ keys,
                         int* __restrict__ clsid, unsigned int* __restrict__ hist1) {
    __shared__ unsigned int lh[2048];
    const int b = blockIdx.y;
    const int a = blockIdx.x * blockDim.x + threadIdx.x;
    for (int i = threadIdx.x; i < 2048; i += blockDim.x) lh[i] = 0;
    __syncthreads();
    if (a < NA) {
        const float4* row = (const float4*)(cls + ((size_t)b * NA + a) * NC);
        float vmax = -1e30f; int vidx = 0;
#pragma unroll
        for (int i = 0; i < NC / 4; ++i) {
            float4 v = row[i];
            if (v.x > vmax) { vmax = v.x; vidx = 4 * i + 0; }
            if (v.y > vmax) { vmax = v.y; vidx = 4 * i + 1; }
            if (v.z > vmax) { vmax = v.z; vidx = 4 * i + 2; }
            if (v.w > vmax) { vmax = v.w; vidx = 4 * i + 3; }
        }
        unsigned int key = (vmax > MIN_SCORE) ? __float_as_uint(vmax) : 0u;
        keys[(size_t)b * NA + a] = key;
        clsid[(size_t)b * NA + a] = vidx;
        atomicAdd(&lh[key >> 21], 1u);
    }
    __syncthreads();
    for (int i = threadIdx.x; i < 2048; i += blockDim.x)
        if (lh[i]) atomicAdd(&hist1[b * 2048 + i], lh[i]);
}

// ---------------- radix-select histogram passes 2 and 3 ----------------
__global__ void k_hist2(const unsigned int* __restrict__ keys, const int* __restrict__ prefix1,
                        unsigned int* __restrict__ hist2) {
    __shared__ unsigned int lh[2048];
    const int b = blockIdx.y;
    const int p = prefix1[b];
    const int a = blockIdx.x * blockDim.x + threadIdx.x;
    for (int i = threadIdx.x; i < 2048; i += blockDim.x) lh[i] = 0;
    __syncthreads();
    if (p >= 0 && a < NA) {
        unsigned int key = keys[(size_t)b * NA + a];
        if ((int)(key >> 21) == p) atomicAdd(&lh[(key >> 10) & 0x7FFu], 1u);
    }
    __syncthreads();
    if (p >= 0)
        for (int i = threadIdx.x; i < 2048; i += blockDim.x)
            if (lh[i]) atomicAdd(&hist2[b * 2048 + i], lh[i]);
}

__global__ void k_hist3(const unsigned int* __restrict__ keys, const int* __restrict__ prefix1,
                        const int* __restrict__ prefix2, unsigned int* __restrict__ hist3) {
    __shared__ unsigned int lh[1024];
    const int b = blockIdx.y;
    const int p1 = prefix1[b];
    const unsigned int p2 = (unsigned int)prefix2[b];
    const int a = blockIdx.x * blockDim.x + threadIdx.x;
    for (int i = threadIdx.x; i < 1024; i += blockDim.x) lh[i] = 0;
    __syncthreads();
    if (p1 >= 0 && a < NA) {
        unsigned int key = keys[(size_t)b * NA + a];
        if ((key >> 10) == p2) atomicAdd(&lh[key & 0x3FFu], 1u);
    }
    __syncthreads();
    if (p1 >= 0)
        for (int i = threadIdx.x; i < 1024; i += blockDim.x)
            if (lh[i]) atomicAdd(&hist3[b * 1024 + i], lh[i]);
}

// ---------------- tiny serial scans (one thread per image, early exit) ----------------
__global__ void k_scan(int mode, const unsigned int* __restrict__ h1,
                       const unsigned int* __restrict__ h2, const unsigned int* __restrict__ h3,
                       int* prefix1, unsigned int* above1, int* prefix2, unsigned int* above2,
                       unsigned int* T) {
    const int b = blockIdx.x;
    if (threadIdx.x != 0) return;
    if (mode == 1) {
        const unsigned int* h = h1 + b * 2048;
        unsigned int cum = 0; int found = -1;
        for (int bin = 2047; bin >= 1; --bin) {
            unsigned int c = h[bin];
            if (cum + c >= TOPN) { found = bin; break; }
            cum += c;
        }
        prefix1[b] = found; above1[b] = cum;
        if (found < 0) T[b] = 1u;  // fewer than TOPN valid -> take all valid keys
    } else if (mode == 2) {
        const int p = prefix1[b]; if (p < 0) return;
        const unsigned int* h = h2 + b * 2048;
        const unsigned int r2 = TOPN - above1[b];
        unsigned int cum = 0;
        for (int bin = 2047; bin >= 0; --bin) {
            unsigned int c = h[bin];
            if (cum + c >= r2) { prefix2[b] = (p << 11) | bin; above2[b] = above1[b] + cum; break; }
            cum += c;
        }
    } else {
        const int p = prefix1[b]; if (p < 0) return;
        const unsigned int* h = h3 + b * 1024;
        const unsigned int r3 = TOPN - above2[b];
        unsigned int cum = 0;
        for (int bin = 1023; bin >= 0; --bin) {
            unsigned int c = h[bin];
            if (cum + c >= r3) { T[b] = ((unsigned int)prefix2[b] << 10) | (unsigned int)bin; break; }
            cum += c;
        }
    }
}

// ---------------- K7: collect all keys >= threshold ----------------
__global__ void k_collect(const unsigned int* __restrict__ keys, const unsigned int* __restrict__ T,
                          unsigned int* __restrict__ n_cand, unsigned long long* __restrict__ cand) {
    const int b = blockIdx.y;
    const int a = blockIdx.x * blockDim.x + threadIdx.x;
    if (a >= NA) return;
    const unsigned int key = keys[(size_t)b * NA + a];
    const unsigned int t = T[b];
    if (key >= t && key != 0u) {
        unsigned int pos = atomicAdd(&n_cand[b], 1u);
        if (pos < CAND_CAP)
            cand[(size_t)b * CAND_CAP + pos] =
                ((unsigned long long)key << 32) | (unsigned int)(0xFFFFFFFFu - (unsigned int)a);
    }
}

// ---------------- K8: sort candidates, decode boxes, greedy NMS, write outputs ----------------
__global__ __launch_bounds__(1024) void k_final(
    const unsigned long long* __restrict__ cand, const unsigned int* __restrict__ n_cand,
    const int* __restrict__ clsid, const float* __restrict__ reg, const float* __restrict__ anch,
    float* __restrict__ out) {
    __shared__ unsigned long long sk[CAND_CAP];
    __shared__ float4 sbox[TOPN];
    __shared__ float ss[TOPN];
    __shared__ float scl[TOPN];
    const int b = blockIdx.x;
    const int tid = threadIdx.x;
    float* out_s = out + b * MAXOBJ;
    float* out_c = out + NB * MAXOBJ + b * MAXOBJ;
    float* out_b = out + 2 * NB * MAXOBJ + b * MAXOBJ * 4;

    // defaults: score/class = -1, boxes = 0
    if (tid < MAXOBJ) { out_s[tid] = -1.0f; out_c[tid] = -1.0f; }
    if (tid < MAXOBJ * 4) out_b[tid] = 0.0f;

    int n = (int)n_cand[b]; if (n > CAND_CAP) n = CAND_CAP;
    for (int i = tid; i < CAND_CAP; i += 1024)
        sk[i] = (i < n) ? cand[(size_t)b * CAND_CAP + i] : 0ull;

    // bitonic sort, descending
    for (int k = 2; k <= CAND_CAP; k <<= 1)
        for (int j = k >> 1; j > 0; j >>= 1) {
            __syncthreads();
            for (int i = tid; i < CAND_CAP; i += 1024) {
                int ixj = i ^ j;
                if (ixj > i) {
                    unsigned long long x = sk[i], y = sk[ixj];
                    bool desc = ((i & k) == 0);
                    if (desc ? (x < y) : (x > y)) { sk[i] = y; sk[ixj] = x; }
                }
            }
        }
    __syncthreads();

    // decode top TOPN candidates
    if (tid < TOPN) {
        unsigned long long e = sk[tid];
        unsigned int key = (unsigned int)(e >> 32);
        if (key != 0u) {
            int a = (int)(0xFFFFFFFFu - (unsigned int)e);
            size_t base = (size_t)b * NA + a;
            float4 r  = ((const float4*)reg)[base];
            float4 an = ((const float4*)anch)[base];
            float aw = an.z - an.x, ah = an.w - an.y;
            float acx = an.x + 0.5f * aw, acy = an.y + 0.5f * ah;
            float pw = expf(r.z) * aw, ph = expf(r.w) * ah;
            float pcx = r.x * aw + acx, pcy = r.y * ah + acy;
            float4 bx;
            bx.x = truncf(pcx - 0.5f * pw); bx.y = truncf(pcy - 0.5f * ph);
            bx.z = truncf(pcx + 0.5f * pw); bx.w = truncf(pcy + 0.5f * ph);
            sbox[tid] = bx;
            ss[tid] = __uint_as_float(key);
            scl[tid] = (float)clsid[base];
        } else {
            sbox[tid] = make_float4(0.f, 0.f, 0.f, 0.f);
            ss[tid] = -1.0f; scl[tid] = -1.0f;
        }
    }
    __syncthreads();
    if (tid >= 64) return;

    // wave 0: greedy NMS; kept boxes live in registers distributed across lanes
    const int lane = tid;
    float k0x1 = 0, k0y1 = 0, k0x2 = 0, k0y2 = 0, k0a = 0;
    float k1x1 = 0, k1y1 = 0, k1x2 = 0, k1y2 = 0, k1a = 0;
    int kc = 0;
    for (int i = 0; i < TOPN; ++i) {
        float4 bi = sbox[i];
        float si = ss[i];
        if (!(si > MIN_SCORE)) break;  // sorted desc: rest are invalid
        float areai = fmaxf((bi.z - bi.x) * (bi.w - bi.y), 1e-4f);
        bool sup = false;
        if (lane < kc) {
            float ix = fminf(k0x2, bi.z) - fmaxf(k0x1, bi.x);
            float iy = fminf(k0y2, bi.w) - fmaxf(k0y1, bi.y);
            float inter = fmaxf(ix, 0.0f) * fmaxf(iy, 0.0f);
            float uni = fmaxf(k0a + areai - inter, 1e-4f);
            sup = (inter / uni) >= NMS_THR;
        }
        if (lane + 64 < kc) {
            float ix = fminf(k1x2, bi.z) - fmaxf(k1x1, bi.x);
            float iy = fminf(k1y2, bi.w) - fmaxf(k1y1, bi.y);
            float inter = fmaxf(ix, 0.0f) * fmaxf(iy, 0.0f);
            float uni = fmaxf(k1a + areai - inter, 1e-4f);
            sup = sup || ((inter / uni) >= NMS_THR);
        }
        if (__ballot(sup) == 0ull) {
            if (lane == 0) {
                out_s[kc] = si;
                out_c[kc] = scl[i];
                out_b[kc * 4 + 0] = bi.x; out_b[kc * 4 + 1] = bi.y;
                out_b[kc * 4 + 2] = bi.z; out_b[kc * 4 + 3] = bi.w;
            }
            if (kc < 64) {
                if (lane == kc) { k0x1 = bi.x; k0y1 = bi.y; k0x2 = bi.z; k0y2 = bi.w; k0a = areai; }
            } else {
                if (lane == kc - 64) { k1x1 = bi.x; k1y1 = bi.y; k1x2 = bi.z; k1y2 = bi.w; k1a = areai; }
            }
            ++kc;
            if (kc >= MAXOBJ) break;
        }
    }
}

extern "C" void kernel_launch(void* const* d_in, const int* in_sizes, int n_in,
                              void* d_out, int out_size, void* d_ws, size_t ws_size,
                              hipStream_t stream) {
    const float* cls  = (const float*)d_in[0];
    const float* reg  = (const float*)d_in[1];
    const float* anch = (const float*)d_in[2];
    float* out = (float*)d_out;
    char* ws = (char*)d_ws;

    unsigned int* keys = (unsigned int*)ws;                                  // 3,200,000 B
    int* clsid = (int*)(ws + 3200000);                                       // 3,200,000 B
    unsigned long long* cand = (unsigned long long*)(ws + 6400000);          // 131,072 B
    char* zbase = ws + 6400000 + 131072;
    unsigned int* h1 = (unsigned int*)zbase;                                 // 65,536 B
    unsigned int* h2 = (unsigned int*)(zbase + 65536);                       // 65,536 B
    unsigned int* h3 = (unsigned int*)(zbase + 131072);                      // 32,768 B
    unsigned int* n_cand  = (unsigned int*)(zbase + 163840);                 // 32 B
    int* prefix1          = (int*)(zbase + 163840 + 32);
    unsigned int* above1  = (unsigned int*)(zbase + 163840 + 64);
    int* prefix2          = (int*)(zbase + 163840 + 96);
    unsigned int* above2  = (unsigned int*)(zbase + 163840 + 128);
    unsigned int* T       = (unsigned int*)(zbase + 163840 + 160);

    hipMemsetAsync(zbase, 0, 163840 + 192, stream);

    dim3 grid((NA + 255) / 256, NB);
    k_scores<<<grid, 256, 0, stream>>>(cls, keys, clsid, h1);
    k_scan<<<NB, 64, 0, stream>>>(1, h1, h2, h3, prefix1, above1, prefix2, above2, T);
    k_hist2<<<grid, 256, 0, stream>>>(keys, prefix1, h2);
    k_scan<<<NB, 64, 0, stream>>>(2, h1, h2, h3, prefix1, above1, prefix2, above2, T);
    k_hist3<<<grid, 256, 0, stream>>>(keys, prefix1, prefix2, h3);
    k_scan<<<NB, 64, 0, stream>>>(3, h1, h2, h3, prefix1, above1, prefix2, above2, T);
    k_collect<<<grid, 256, 0, stream>>>(keys, T, n_cand, cand);
    k_final<<<NB, 1024, 0, stream>>>(cand, n_cand, clsid, reg, anch, out);
}

// Round 2
// 508.027 us; speedup vs baseline: 1.3834x; 1.3834x over previous
//
#include <hip/hip_runtime.h>
#include <cstdint>

#define NB 8
#define NA 100000
#define NC 80
#define TOPN 1000
#define MAXOBJ 100
#define CAND_CAP 2048
#define MIN_SCORE 0.05f
#define NMS_THR 0.5f

// ---------------- K1: per-anchor max/argmax over classes, fully coalesced ----------------
// Block = 320 threads (5 waves) handles 16 anchors (16*80 = 1280 floats = 320 float4).
// Thread t loads float4 #t of the block's contiguous 5120B chunk -> 16B/lane coalesced.
__global__ __launch_bounds__(320) void k_scores(const float* __restrict__ cls,
                                                unsigned int* __restrict__ keys,
                                                int* __restrict__ clsid) {
    __shared__ float sval[320];
    __shared__ int sidx[320];
    const int b = blockIdx.y;
    const int a0 = blockIdx.x * 16;
    const int t = threadIdx.x;
    const float4* base = (const float4*)(cls + ((size_t)b * NA + a0) * NC);
    float4 v = base[t];
    float m = v.x; int ix = 0;
    if (v.y > m) { m = v.y; ix = 1; }
    if (v.z > m) { m = v.z; ix = 2; }
    if (v.w > m) { m = v.w; ix = 3; }
    const int e = t % 20;  // float4 index within anchor
    sval[t] = m;
    sidx[t] = e * 4 + ix;
    __syncthreads();
    if (t < 16) {
        float vm = sval[t * 20]; int vi = sidx[t * 20];
        for (int i = 1; i < 20; ++i) {
            float x = sval[t * 20 + i];
            if (x > vm) { vm = x; vi = sidx[t * 20 + i]; }
        }
        size_t o = (size_t)b * NA + a0 + t;
        keys[o] = (vm > MIN_SCORE) ? __float_as_uint(vm) : 0u;
        clsid[o] = vi;
    }
}

// wave-aggregated LDS histogram add (cheap when few distinct bins per wave)
__device__ inline void wave_agg_hist(unsigned int* lh, int bin, bool pred) {
    unsigned long long active = __ballot(pred);
    const int lane = threadIdx.x & 63;
    while (active) {
        int leader = (int)__builtin_ctzll(active);
        int lbin = __shfl(bin, leader);
        unsigned long long mask = __ballot(pred && (bin == lbin));
        if (lane == leader) atomicAdd(&lh[lbin], (unsigned int)__popcll(mask));
        active &= ~mask;
    }
}

// One wave (tid<64): find bin such that sum of bins above it < rank <= sum incl. bin.
// Scans from TOP. Writes {bin, count_above} to LDS; bin=-1 if total < rank.
__device__ inline void top_threshold(const unsigned int* lh, int nbins, int minbin,
                                     unsigned int rank, int* out_bin, unsigned int* out_above) {
    const int lane = threadIdx.x;  // caller guarantees tid < 64
    const int chunk = nbins >> 6;
    const int hi = nbins - 1 - lane * chunk;
    const int lo = hi - chunk + 1;
    unsigned int s = 0;
    for (int i = hi; i >= lo; --i)
        if (i >= minbin) s += lh[i];
    unsigned int incl = s;
    for (int d = 1; d < 64; d <<= 1) {
        unsigned int o = __shfl_up(incl, d);
        if (lane >= d) incl += o;
    }
    unsigned int pre = incl - s;
    bool hit = (pre < rank) && (incl >= rank);
    unsigned long long m = __ballot(hit);
    if (m == 0ull) {
        if (lane == 0) { *out_bin = -1; *out_above = 0; }
        return;
    }
    if (hit) {
        unsigned int cum = pre;
        int fb = -1;
        for (int i = hi; i >= lo; --i) {
            if (i < minbin) break;
            unsigned int c = lh[i];
            if (cum + c >= rank) { fb = i; break; }
            cum += c;
        }
        *out_bin = fb;
        *out_above = cum;
    }
}

// ---------------- K2: per-image select + sort + decode + NMS + output ----------------
__global__ __launch_bounds__(1024) void k_mega(
    const unsigned int* __restrict__ keys, const int* __restrict__ clsid,
    const float* __restrict__ reg, const float* __restrict__ anch,
    float* __restrict__ out) {
    __shared__ unsigned int lh[2048];
    __shared__ unsigned long long sk[CAND_CAP];
    __shared__ float4 sbox[TOPN];
    __shared__ float ss[TOPN];
    __shared__ float scl[TOPN];
    __shared__ int s_bin;
    __shared__ unsigned int s_above;
    __shared__ unsigned int s_cnt;

    const int b = blockIdx.x;
    const int tid = threadIdx.x;
    const int lane = tid & 63;
    const unsigned int* kb = keys + (size_t)b * NA;
    float* out_s = out + b * MAXOBJ;
    float* out_c = out + NB * MAXOBJ + b * MAXOBJ;
    float* out_b = out + 2 * NB * MAXOBJ + b * MAXOBJ * 4;

    if (tid < MAXOBJ) { out_s[tid] = -1.0f; out_c[tid] = -1.0f; }
    if (tid < MAXOBJ * 4) out_b[tid] = 0.0f;

    // ---- pass 1: 11-bit MSB histogram (keys concentrate -> wave-aggregated atomics) ----
    for (int i = tid; i < 2048; i += 1024) lh[i] = 0;
    __syncthreads();
    for (int base = 0; base < NA; base += 1024) {
        int a = base + tid;
        bool p = a < NA;
        unsigned int key = p ? kb[a] : 0u;
        wave_agg_hist(lh, (int)(key >> 21), p);
    }
    __syncthreads();
    if (tid < 64) top_threshold(lh, 2048, 1, TOPN, &s_bin, &s_above);
    __syncthreads();
    const int p1 = s_bin;
    const unsigned int above1 = s_above;

    unsigned int T;
    if (p1 < 0) {
        T = 1u;  // fewer than TOPN valid: take all nonzero keys
    } else {
        // ---- pass 2: next 11 bits within bin p1 (spread -> plain atomics) ----
        __syncthreads();
        for (int i = tid; i < 2048; i += 1024) lh[i] = 0;
        __syncthreads();
        for (int base = 0; base < NA; base += 1024) {
            int a = base + tid;
            if (a < NA) {
                unsigned int key = kb[a];
                if ((int)(key >> 21) == p1) atomicAdd(&lh[(key >> 10) & 0x7FFu], 1u);
            }
        }
        __syncthreads();
        if (tid < 64) top_threshold(lh, 2048, 0, TOPN - above1, &s_bin, &s_above);
        __syncthreads();
        const int p2 = s_bin;
        const unsigned int above2 = above1 + s_above;
        if (p2 < 0) {
            T = 1u;
        } else {
            // ---- pass 3: low 10 bits within (p1,p2) ----
            const unsigned int pref = ((unsigned int)p1 << 11) | (unsigned int)p2;
            __syncthreads();
            for (int i = tid; i < 1024; i += 1024) lh[i] = 0;
            __syncthreads();
            for (int base = 0; base < NA; base += 1024) {
                int a = base + tid;
                if (a < NA) {
                    unsigned int key = kb[a];
                    if ((key >> 10) == pref) atomicAdd(&lh[key & 0x3FFu], 1u);
                }
            }
            __syncthreads();
            if (tid < 64) top_threshold(lh, 1024, 0, TOPN - above2, &s_bin, &s_above);
            __syncthreads();
            const int p3 = s_bin;
            T = (p3 < 0) ? 1u : ((pref << 10) | (unsigned int)p3);
        }
    }
    __syncthreads();

    // ---- collect keys >= T (ballot-compacted, one LDS atomic per wave per chunk) ----
    for (int i = tid; i < CAND_CAP; i += 1024) sk[i] = 0ull;
    if (tid == 0) s_cnt = 0;
    __syncthreads();
    for (int base = 0; base < NA; base += 1024) {
        int a = base + tid;
        unsigned int key = (a < NA) ? kb[a] : 0u;
        bool w = (key >= T) && (key != 0u);
        unsigned long long m = __ballot(w);
        if (m) {
            int leader = (int)__builtin_ctzll(m);
            unsigned int base_slot = 0;
            if (lane == leader) base_slot = atomicAdd(&s_cnt, (unsigned int)__popcll(m));
            base_slot = __shfl(base_slot, leader);
            unsigned int off = (unsigned int)__popcll(m & ((1ull << lane) - 1ull));
            unsigned int pos = base_slot + off;
            if (w && pos < CAND_CAP)
                sk[pos] = ((unsigned long long)key << 32) |
                          (unsigned long long)(0xFFFFFFFFu - (unsigned int)a);
        }
    }
    __syncthreads();

    // ---- bitonic sort, descending ----
    for (int k = 2; k <= CAND_CAP; k <<= 1)
        for (int j = k >> 1; j > 0; j >>= 1) {
            __syncthreads();
            for (int i = tid; i < CAND_CAP; i += 1024) {
                int ixj = i ^ j;
                if (ixj > i) {
                    unsigned long long x = sk[i], y = sk[ixj];
                    bool desc = ((i & k) == 0);
                    if (desc ? (x < y) : (x > y)) { sk[i] = y; sk[ixj] = x; }
                }
            }
        }
    __syncthreads();

    // ---- decode top TOPN ----
    if (tid < TOPN) {
        unsigned long long e = sk[tid];
        unsigned int key = (unsigned int)(e >> 32);
        if (key != 0u) {
            int a = (int)(0xFFFFFFFFu - (unsigned int)e);
            size_t base = (size_t)b * NA + a;
            float4 r  = ((const float4*)reg)[base];
            float4 an = ((const float4*)anch)[base];
            float aw = an.z - an.x, ah = an.w - an.y;
            float acx = an.x + 0.5f * aw, acy = an.y + 0.5f * ah;
            float pw = expf(r.z) * aw, ph = expf(r.w) * ah;
            float pcx = r.x * aw + acx, pcy = r.y * ah + acy;
            float4 bx;
            bx.x = truncf(pcx - 0.5f * pw); bx.y = truncf(pcy - 0.5f * ph);
            bx.z = truncf(pcx + 0.5f * pw); bx.w = truncf(pcy + 0.5f * ph);
            sbox[tid] = bx;
            ss[tid] = __uint_as_float(key);
            scl[tid] = (float)clsid[base];
        } else {
            sbox[tid] = make_float4(0.f, 0.f, 0.f, 0.f);
            ss[tid] = -1.0f;
            scl[tid] = -1.0f;
        }
    }
    __syncthreads();
    if (tid >= 64) return;

    // ---- wave 0: greedy NMS; kept boxes in registers distributed across lanes ----
    float k0x1 = 0, k0y1 = 0, k0x2 = 0, k0y2 = 0, k0a = 0;
    float k1x1 = 0, k1y1 = 0, k1x2 = 0, k1y2 = 0, k1a = 0;
    int kc = 0;
    for (int i = 0; i < TOPN; ++i) {
        float4 bi = sbox[i];
        float si = ss[i];
        if (!(si > MIN_SCORE)) break;  // sorted desc: rest invalid
        float areai = fmaxf((bi.z - bi.x) * (bi.w - bi.y), 1e-4f);
        bool sup = false;
        if (lane < kc) {
            float ix = fminf(k0x2, bi.z) - fmaxf(k0x1, bi.x);
            float iy = fminf(k0y2, bi.w) - fmaxf(k0y1, bi.y);
            float inter = fmaxf(ix, 0.0f) * fmaxf(iy, 0.0f);
            float uni = fmaxf(k0a + areai - inter, 1e-4f);
            sup = (inter / uni) >= NMS_THR;
        }
        if (lane + 64 < kc) {
            float ix = fminf(k1x2, bi.z) - fmaxf(k1x1, bi.x);
            float iy = fminf(k1y2, bi.w) - fmaxf(k1y1, bi.y);
            float inter = fmaxf(ix, 0.0f) * fmaxf(iy, 0.0f);
            float uni = fmaxf(k1a + areai - inter, 1e-4f);
            sup = sup || ((inter / uni) >= NMS_THR);
        }
        if (__ballot(sup) == 0ull) {
            if (lane == 0) {
                out_s[kc] = si;
                out_c[kc] = scl[i];
                out_b[kc * 4 + 0] = bi.x; out_b[kc * 4 + 1] = bi.y;
                out_b[kc * 4 + 2] = bi.z; out_b[kc * 4 + 3] = bi.w;
            }
            if (kc < 64) {
                if (lane == kc) { k0x1 = bi.x; k0y1 = bi.y; k0x2 = bi.z; k0y2 = bi.w; k0a = areai; }
            } else {
                if (lane == kc - 64) { k1x1 = bi.x; k1y1 = bi.y; k1x2 = bi.z; k1y2 = bi.w; k1a = areai; }
            }
            ++kc;
            if (kc >= MAXOBJ) break;
        }
    }
}

extern "C" void kernel_launch(void* const* d_in, const int* in_sizes, int n_in,
                              void* d_out, int out_size, void* d_ws, size_t ws_size,
                              hipStream_t stream) {
    const float* cls  = (const float*)d_in[0];
    const float* reg  = (const float*)d_in[1];
    const float* anch = (const float*)d_in[2];
    float* out = (float*)d_out;
    char* ws = (char*)d_ws;

    unsigned int* keys = (unsigned int*)ws;             // 3,200,000 B
    int* clsid = (int*)(ws + 3200000);                  // 3,200,000 B

    dim3 grid1(NA / 16, NB);  // 6250 x 8, 16 anchors per 320-thread block
    k_scores<<<grid1, 320, 0, stream>>>(cls, keys, clsid);
    k_mega<<<NB, 1024, 0, stream>>>(keys, clsid, reg, anch, out);
}